// Round 5
// baseline (2468.651 us; speedup 1.0000x reference)
//
#include <hip/hip_runtime.h>

typedef float vf2 __attribute__((ext_vector_type(2)));

__device__ __forceinline__ vf2 cmulv(vf2 a, vf2 b){
  vf2 br; br.x = -b.y; br.y = b.x;
  return a.x*b + a.y*br;
}

#define ROWS 66   // transpose-buffer row stride in float2 (64 + 2 pad -> bank stagger)

__global__ __attribute__((amdgpu_flat_work_group_size(64,64)))
__attribute__((amdgpu_waves_per_eu(1,1)))
void qiddm_wave(const float* __restrict__ gx,
                const float* __restrict__ gcw,
                const float* __restrict__ gcb,
                const float* __restrict__ gw1,
                const float* __restrict__ glw,
                const float* __restrict__ glb,
                float* __restrict__ gout)
{
  // One wave (64 lanes) per sample. Whole 4096-amp state in registers:
  // L0 layout: lane u = idx bits 11..6 (wires 0..5), reg w = idx bits 5..0 (wires 6..11)
  // L1 layout: lane u = idx bits 5..0,  reg w = idx bits 11..6
  __shared__ vf2 xbuf[64 * ROWS];   // 33792 B transpose buffer (aliases conv image)
  __shared__ vf2 tabs[5][64];       // merged-diagonal tables over the reg domain
  __shared__ vf2 scsl[72];          // (cos, sin) of theta/2 per (sublayer, wire)

  const int u = threadIdx.x;        // lane 0..63
  const int bid = blockIdx.x;

  float xr[12];                     // circuit inputs / expvals (wave-uniform values)

  // ---------- conv 3x3 s2 p1 + bias + GAP ----------
  {
    float* img = (float*)xbuf;
#pragma unroll
    for (int i = 0; i < 4; i++){
      float4 q4 = ((const float4*)gx)[(size_t)bid * 256 + i * 64 + u];
      ((float4*)img)[i * 64 + u] = q4;
    }
    float p[4][9];
#pragma unroll
    for (int i = 0; i < 4; i++){
      int pos = u + 64 * i, oi = pos >> 4, oj = pos & 15;
#pragma unroll
      for (int ki = 0; ki < 3; ki++)
#pragma unroll
        for (int kj = 0; kj < 3; kj++){
          int ri = 2*oi - 1 + ki, cj = 2*oj - 1 + kj;
          p[i][ki*3+kj] = (ri >= 0 && ri < 32 && cj >= 0 && cj < 32) ? img[ri*32+cj] : 0.0f;
        }
    }
#pragma unroll
    for (int q = 0; q < 12; q++){
      float a = 0.0f;
#pragma unroll
      for (int e = 0; e < 9; e++){
        float wv = gcw[q*9+e];                  // uniform -> scalarized
#pragma unroll
        for (int i = 0; i < 4; i++) a += p[i][e] * wv;
      }
#pragma unroll
      for (int off = 32; off; off >>= 1) a += __shfl_xor(a, off);
      xr[q] = gcb[q] + a * (1.0f/256.0f);
    }
  }

  vf2 v[64];

#pragma unroll 1
  for (int n = 0; n < 2; n++){
    const float* W = gw1 + n * 216;

    // alpha(d,j): merged-diagonal angle for wire j of diagonal d (uniform value)
    auto alpha = [&](int d, int j)->float{
      int i = d >> 1;
      if (d & 1) return W[((i*2+1)*12+j)*3+0] + W[((i*2+0)*12+j)*3+2];
      else       return W[((i*2+0)*12+j)*3+0] + xr[j] + W[(((i-1)*2+1)*12+j)*3+2];
    };

    // ---- build RY cos/sin table (72 gates) ----
#pragma unroll
    for (int rep = 0; rep < 2; rep++){
      int e = u + rep * 64;
      if (e < 72){
        float sv, cv; __sincosf(0.5f * W[e*3+1], &sv, &cv);
        vf2 cs; cs.x = cv; cs.y = sv; scsl[e] = cs;
      }
    }

    // ---- build 5 diagonal tables over the reg domain (lane u builds entry u) ----
#pragma unroll
    for (int d = 1; d <= 5; d++){
      const int par = d & 1;                    // 1 -> applied in L1 (r=1), 0 -> L0 (r=2)
      const int r = par ? 1 : 2;
      float ph = 0.0f;
#pragma unroll
      for (int lb = 0; lb < 6; lb++){
        int wire = par ? (5 - lb) : (11 - lb);  // reg-domain wires
        ph += alpha(d, wire) * ((float)((u >> lb) & 1) - 0.5f);
      }
      int idx_r = par ? (u << 6) : u;           // embed reg bits at their idx positions
      int y = ((idx_r << r) | (idx_r >> (12 - r))) & 0xFFF;
      int s = __popc(idx_r & y) & 1;            // within-reg CZ parity
      float sv, cv; __sincosf(ph, &sv, &cv);
      vf2 e; e.x = cv; e.y = sv; if (s) e = -e;
      tabs[d-1][u] = e;
    }

    // ---- helpers ----
    auto gates6 = [&](int sl, int par){         // 6 RY gates on the reg bits
#pragma unroll
      for (int lb = 0; lb < 6; lb++){
        int wire = par ? (5 - lb) : (11 - lb);
        vf2 cs = scsl[sl*12 + wire];
        const float c = cs.x, sn = cs.y;
#pragma unroll
        for (int w0 = 0; w0 < 64; w0++){
          if (w0 & (1 << lb)) continue;
          const int w1 = w0 | (1 << lb);
          vf2 a = v[w0], b = v[w1];
          v[w0] = c*a - sn*b;
          v[w1] = sn*a + c*b;
        }
      }
    };

    auto transpose = [&](){                     // swap lane-domain <-> reg-domain
#pragma unroll
      for (int w = 0; w < 64; w++) xbuf[w * ROWS + u] = v[w];     // conflict-free b64
      const float4* rp = (const float4*)&xbuf[u * ROWS];          // 528B row, 16B aligned
#pragma unroll
      for (int j = 0; j < 32; j++){                               // conflict-free b128
        float4 f = rp[j];
        v[2*j].x = f.x; v[2*j].y = f.y;
        v[2*j+1].x = f.z; v[2*j+1].y = f.w;
      }
    };

    auto diag = [&](int d, int par){            // par compile-folds at each call site
      const int r = par ? 1 : 2;
      float ph = 0.0f;
#pragma unroll
      for (int lb = 0; lb < 6; lb++){
        int wire = par ? (11 - lb) : (5 - lb);  // lane-domain wires
        ph += alpha(d, wire) * ((float)((u >> lb) & 1) - 0.5f);
      }
      int idx_l = par ? u : (u << 6);
      int y = ((idx_l << r) | (idx_l >> (12 - r))) & 0xFFF;
      int s_l = __popc(idx_l & y) & 1;          // within-lane CZ parity
      float sv, cv; __sincosf(ph, &sv, &cv);
      vf2 lp; lp.x = cv; lp.y = sv; if (s_l) lp = -lp;
      vf2 lpn = -lp;
      const int u0 = u & 1, u1 = (u >> 1) & 1, u4 = (u >> 4) & 1, u5 = (u >> 5) & 1;
#pragma unroll
      for (int w = 0; w < 64; w++){
        vf2 dph = tabs[d-1][w];                 // broadcast read (uniform value)
        int sx;                                 // cross-boundary CZ terms (w folds)
        if (par) sx = ((w & 1) * u5) ^ (((w >> 5) & 1) * u0);
        else     sx = (((w >> 5) & 1) * u1) ^ (((w >> 4) & 1) * u0)
                    ^ (((w >> 1) & 1) * u5) ^ ((w & 1) * u4);
        vf2 t = cmulv(v[w], dph);
        v[w] = cmulv(t, sx ? lpn : lp);
      }
    };

    // ---- circuit: |0>, 6 sublayers, 6 transposes, D1..D5, measure ----
#pragma unroll
    for (int w = 0; w < 64; w++){ v[w].x = 0.f; v[w].y = 0.f; }
    if (u == 0) v[0].x = 1.f;                   // idx 0 = (lane 0, reg 0)

    gates6(0, 0);                               // s0 on wires 6..11 (L0)
#pragma unroll 1
    for (int m = 0; m < 3; m++){
      transpose();                              // -> L1
      gates6(2*m, 1);                           // s_{2m} on wires 0..5
      diag(2*m + 1, 1);                         // D_{2m+1} (r=1) in L1
      gates6(2*m + 1, 1);                       // s_{2m+1} on wires 0..5
      transpose();                              // -> L0
      gates6(2*m + 1, 0);                       // s_{2m+1} on wires 6..11
      if (m < 2){
        diag(2*m + 2, 0);                       // D_{2m+2} (r=2) in L0
        gates6(2*m + 2, 0);                     // s_{2m+2} on wires 6..11
      }
    }

    // ---- measurement in L0 (final omega-diagonal is a pure phase: dropped) ----
    {
      float P = 0.f, mm[6] = {0.f,0.f,0.f,0.f,0.f,0.f};  // wires 6..11 (reg bits 5..0)
#pragma unroll
      for (int w = 0; w < 64; w++){
        float pr = v[w].x*v[w].x + v[w].y*v[w].y;
        P += pr;
#pragma unroll
        for (int i = 0; i < 6; i++)
          mm[i] += ((w >> (5 - i)) & 1) ? -pr : pr;
      }
#pragma unroll
      for (int q = 0; q < 12; q++){
        float val = (q < 6) ? (((u >> (5 - q)) & 1) ? -P : P)   // wires 0..5 (lane bits)
                            : mm[q - 6];
#pragma unroll
        for (int off = 32; off; off >>= 1) val += __shfl_xor(val, off);
        xr[q] = val;                            // uniform across lanes after butterfly
      }
    }
  }

  // ---------- final linear ----------
  {
#pragma unroll
    for (int i = 0; i < 16; i++){
      int o = i * 64 + u;
      const float4* wr = (const float4*)(glw + o * 12);   // 48B rows, 16B aligned
      float4 w0 = wr[0], w1 = wr[1], w2 = wr[2];
      float a = glb[o];
      a += xr[0]*w0.x + xr[1]*w0.y + xr[2]*w0.z + xr[3]*w0.w;
      a += xr[4]*w1.x + xr[5]*w1.y + xr[6]*w1.z + xr[7]*w1.w;
      a += xr[8]*w2.x + xr[9]*w2.y + xr[10]*w2.z + xr[11]*w2.w;
      gout[(size_t)bid * 1024 + o] = a;
    }
  }
}

extern "C" void kernel_launch(void* const* d_in, const int* in_sizes, int n_in,
                              void* d_out, int out_size, void* d_ws, size_t ws_size,
                              hipStream_t stream)
{
  (void)n_in; (void)d_ws; (void)ws_size; (void)out_size;
  const float* x  = (const float*)d_in[0];
  const float* cw = (const float*)d_in[1];
  const float* cb = (const float*)d_in[2];
  const float* w1 = (const float*)d_in[3];
  const float* lw = (const float*)d_in[4];
  const float* lb = (const float*)d_in[5];
  float* out = (float*)d_out;
  const int nb = in_sizes[0] / 1024;   // 2048 samples, one wave each
  hipLaunchKernelGGL(qiddm_wave, dim3(nb), dim3(64), 0, stream,
                     x, cw, cb, w1, lw, lb, out);
}

// Round 6
// 452.186 us; speedup vs baseline: 5.4594x; 5.4594x over previous
//
#include <hip/hip_runtime.h>

typedef float vf2 __attribute__((ext_vector_type(2)));

__device__ __forceinline__ vf2 cmulv(vf2 a, vf2 b){
  vf2 br; br.x = -b.y; br.y = b.x;
  return a.x*b + a.y*br;
}

#define ROWS 66   // transpose-buffer row stride in float2 (64 + 2 pad -> bank stagger)

// merged-diagonal angle for wire j of diagonal d (wave-uniform value); d compile-time
#define ALPHA(d, j) (((d) & 1) \
  ? (W[((((d)>>1)*2+1)*12+(j))*3+0] + W[((((d)>>1)*2+0)*12+(j))*3+2]) \
  : (W[((((d)>>1)*2+0)*12+(j))*3+0] + xr[(j)] + W[(((((d)>>1)-1)*2+1)*12+(j))*3+2]))

// 6 RY gates on the reg-domain bits. No lambdas: plain macro on v[] (keeps SROA happy).
#define GATES6(sl, par) do{ \
  _Pragma("unroll") \
  for (int lb = 0; lb < 6; lb++){ \
    const int wire_ = (par) ? (5 - lb) : (11 - lb); \
    vf2 cs_ = scsl[(sl)*12 + wire_]; \
    const float c_ = cs_.x, sn_ = cs_.y; \
    _Pragma("unroll") \
    for (int w0 = 0; w0 < 64; w0++){ \
      if (w0 & (1 << lb)) continue; \
      const int w1 = w0 | (1 << lb); \
      vf2 a_ = v[w0], b_ = v[w1]; \
      v[w0] = c_*a_ - sn_*b_; \
      v[w1] = sn_*a_ + c_*b_; \
    } \
  } \
}while(0)

// swap lane-domain <-> reg-domain through LDS (conflict-free b64 writes / b128 reads)
#define TRANSPOSE() do{ \
  _Pragma("unroll") \
  for (int w = 0; w < 64; w++) xbuf[w * ROWS + u] = v[w]; \
  _Pragma("unroll") \
  for (int j = 0; j < 32; j++){ \
    float4 f_ = ((const float4*)&xbuf[u * ROWS])[j]; \
    v[2*j].x = f_.x; v[2*j].y = f_.y; \
    v[2*j+1].x = f_.z; v[2*j+1].y = f_.w; \
  } \
}while(0)

// merged diagonal d: reg-part from tabs, lane-part built here, CZ cross terms explicit
#define DIAG(d, par) do{ \
  const int r_ = (par) ? 1 : 2; \
  float ph_ = 0.0f; \
  _Pragma("unroll") \
  for (int lb = 0; lb < 6; lb++){ \
    const int wire_ = (par) ? (11 - lb) : (5 - lb); \
    ph_ += ALPHA(d, wire_) * ((float)((u >> lb) & 1) - 0.5f); \
  } \
  const int idxl_ = (par) ? u : (u << 6); \
  const int y_ = ((idxl_ << r_) | (idxl_ >> (12 - r_))) & 0xFFF; \
  const int sl_ = __popc(idxl_ & y_) & 1; \
  float sv_, cv_; __sincosf(ph_, &sv_, &cv_); \
  vf2 lp_; lp_.x = cv_; lp_.y = sv_; if (sl_) lp_ = -lp_; \
  vf2 lpn_ = -lp_; \
  const int u0_ = u & 1, u1_ = (u >> 1) & 1, u4_ = (u >> 4) & 1, u5_ = (u >> 5) & 1; \
  _Pragma("unroll") \
  for (int w = 0; w < 64; w++){ \
    vf2 dph_ = tabs[(d)-1][w]; \
    int sx_; \
    if (par) sx_ = ((w & 1) * u5_) ^ (((w >> 5) & 1) * u0_); \
    else     sx_ = (((w >> 5) & 1) * u1_) ^ (((w >> 4) & 1) * u0_) \
                 ^ (((w >> 1) & 1) * u5_) ^ ((w & 1) * u4_); \
    vf2 t_ = cmulv(v[w], dph_); \
    v[w] = cmulv(t_, sx_ ? lpn_ : lp_); \
  } \
}while(0)

__global__ __attribute__((amdgpu_flat_work_group_size(64,64)))
__attribute__((amdgpu_waves_per_eu(1,1)))
void qiddm_wave(const float* __restrict__ gx,
                const float* __restrict__ gcw,
                const float* __restrict__ gcb,
                const float* __restrict__ gw1,
                const float* __restrict__ glw,
                const float* __restrict__ glb,
                float* __restrict__ gout)
{
  // One wave (64 lanes) per sample; whole 4096-amp state in registers.
  // L0 layout: lane u = idx bits 11..6 (wires 0..5), reg w = idx bits 5..0 (wires 6..11)
  // L1 layout: lane u = idx bits 5..0,  reg w = idx bits 11..6
  __shared__ vf2 xbuf[64 * ROWS];   // 33792 B transpose buffer (aliases conv image)
  __shared__ vf2 tabs[5][64];       // merged-diagonal tables over the reg domain
  __shared__ vf2 scsl[72];          // (cos, sin) of theta/2 per (sublayer, wire)

  const int u = threadIdx.x;        // lane 0..63
  const int bid = blockIdx.x;

  float xr[12];                     // circuit inputs / expvals (wave-uniform values)

  // ---------- conv 3x3 s2 p1 + bias + GAP ----------
  {
    float* img = (float*)xbuf;
#pragma unroll
    for (int i = 0; i < 4; i++){
      float4 q4 = ((const float4*)gx)[(size_t)bid * 256 + i * 64 + u];
      ((float4*)img)[i * 64 + u] = q4;
    }
    float p[4][9];
#pragma unroll
    for (int i = 0; i < 4; i++){
      int pos = u + 64 * i, oi = pos >> 4, oj = pos & 15;
#pragma unroll
      for (int ki = 0; ki < 3; ki++)
#pragma unroll
        for (int kj = 0; kj < 3; kj++){
          int ri = 2*oi - 1 + ki, cj = 2*oj - 1 + kj;
          p[i][ki*3+kj] = (ri >= 0 && ri < 32 && cj >= 0 && cj < 32) ? img[ri*32+cj] : 0.0f;
        }
    }
#pragma unroll
    for (int q = 0; q < 12; q++){
      float a = 0.0f;
#pragma unroll
      for (int e = 0; e < 9; e++){
        float wv = gcw[q*9+e];                  // uniform -> scalarized
#pragma unroll
        for (int i = 0; i < 4; i++) a += p[i][e] * wv;
      }
#pragma unroll
      for (int off = 32; off; off >>= 1) a += __shfl_xor(a, off);
      xr[q] = gcb[q] + a * (1.0f/256.0f);
    }
  }

  vf2 v[64];

#pragma unroll 1
  for (int n = 0; n < 2; n++){
    const float* W = gw1 + n * 216;

    // ---- build RY cos/sin table (72 gates) ----
#pragma unroll
    for (int rep = 0; rep < 2; rep++){
      int e = u + rep * 64;
      if (e < 72){
        float sv, cv; __sincosf(0.5f * W[e*3+1], &sv, &cv);
        vf2 cs; cs.x = cv; cs.y = sv; scsl[e] = cs;
      }
    }

    // ---- build 5 diagonal tables over the reg domain (lane u builds entry u) ----
#pragma unroll
    for (int d = 1; d <= 5; d++){
      const int par = d & 1;                    // 1 -> applied in L1 (r=1), 0 -> L0 (r=2)
      const int r = par ? 1 : 2;
      float ph = 0.0f;
#pragma unroll
      for (int lb = 0; lb < 6; lb++){
        int wire = par ? (5 - lb) : (11 - lb);  // reg-domain wires
        ph += ALPHA(d, wire) * ((float)((u >> lb) & 1) - 0.5f);
      }
      int idx_r = par ? (u << 6) : u;           // embed reg bits at their idx positions
      int y = ((idx_r << r) | (idx_r >> (12 - r))) & 0xFFF;
      int s = __popc(idx_r & y) & 1;            // within-reg CZ parity
      float sv, cv; __sincosf(ph, &sv, &cv);
      vf2 e; e.x = cv; e.y = sv; if (s) e = -e;
      tabs[d-1][u] = e;
    }

    // ---- circuit: |0>, 6 sublayers, 6 transposes, D1..D5, measure ----
#pragma unroll
    for (int w = 0; w < 64; w++){ v[w].x = 0.f; v[w].y = 0.f; }
    if (u == 0) v[0].x = 1.f;                   // idx 0 = (lane 0, reg 0)

    GATES6(0, 0);                               // s0 on wires 6..11 (L0)
#pragma unroll
    for (int m = 0; m < 3; m++){
      TRANSPOSE();                              // -> L1
      GATES6(2*m, 1);                           // s_{2m} on wires 0..5
      DIAG(2*m + 1, 1);                         // D_{2m+1} (r=1) in L1
      GATES6(2*m + 1, 1);                       // s_{2m+1} on wires 0..5
      TRANSPOSE();                              // -> L0
      GATES6(2*m + 1, 0);                       // s_{2m+1} on wires 6..11
      if (m < 2){
        DIAG(2*m + 2, 0);                       // D_{2m+2} (r=2) in L0
        GATES6(2*m + 2, 0);                     // s_{2m+2} on wires 6..11
      }
    }

    // ---- measurement in L0 (final omega-diagonal is a pure phase: dropped) ----
    {
      float P = 0.f, mm[6] = {0.f,0.f,0.f,0.f,0.f,0.f};  // wires 6..11 (reg bits 5..0)
#pragma unroll
      for (int w = 0; w < 64; w++){
        float pr = v[w].x*v[w].x + v[w].y*v[w].y;
        P += pr;
#pragma unroll
        for (int i = 0; i < 6; i++)
          mm[i] += ((w >> (5 - i)) & 1) ? -pr : pr;
      }
#pragma unroll
      for (int q = 0; q < 12; q++){
        float val = (q < 6) ? (((u >> (5 - q)) & 1) ? -P : P)   // wires 0..5 (lane bits)
                            : mm[q - 6];
#pragma unroll
        for (int off = 32; off; off >>= 1) val += __shfl_xor(val, off);
        xr[q] = val;                            // uniform across lanes after butterfly
      }
    }
  }

  // ---------- final linear ----------
  {
#pragma unroll
    for (int i = 0; i < 16; i++){
      int o = i * 64 + u;
      const float4* wr = (const float4*)(glw + o * 12);   // 48B rows, 16B aligned
      float4 w0 = wr[0], w1 = wr[1], w2 = wr[2];
      float a = glb[o];
      a += xr[0]*w0.x + xr[1]*w0.y + xr[2]*w0.z + xr[3]*w0.w;
      a += xr[4]*w1.x + xr[5]*w1.y + xr[6]*w1.z + xr[7]*w1.w;
      a += xr[8]*w2.x + xr[9]*w2.y + xr[10]*w2.z + xr[11]*w2.w;
      gout[(size_t)bid * 1024 + o] = a;
    }
  }
}

extern "C" void kernel_launch(void* const* d_in, const int* in_sizes, int n_in,
                              void* d_out, int out_size, void* d_ws, size_t ws_size,
                              hipStream_t stream)
{
  (void)n_in; (void)d_ws; (void)ws_size; (void)out_size;
  const float* x  = (const float*)d_in[0];
  const float* cw = (const float*)d_in[1];
  const float* cb = (const float*)d_in[2];
  const float* w1 = (const float*)d_in[3];
  const float* lw = (const float*)d_in[4];
  const float* lb = (const float*)d_in[5];
  float* out = (float*)d_out;
  const int nb = in_sizes[0] / 1024;   // 2048 samples, one wave each
  hipLaunchKernelGGL(qiddm_wave, dim3(nb), dim3(64), 0, stream,
                     x, cw, cb, w1, lw, lb, out);
}

// Round 7
// 214.237 us; speedup vs baseline: 11.5230x; 2.1107x over previous
//
#include <hip/hip_runtime.h>

typedef float vf2  __attribute__((ext_vector_type(2)));
typedef float v128f __attribute__((ext_vector_type(128)));

__device__ __forceinline__ vf2 cmulv(vf2 a, vf2 b){
  vf2 br; br.x = -b.y; br.y = b.x;
  return a.x*b + a.y*br;
}

#define ROWS 66   // transpose-buffer row stride in float2 (64 + 2 pad -> bank stagger)

// merged-diagonal angle for wire j of diagonal d (wave-uniform); d, j compile-time
#define ALPHA(d, j) (((d) & 1) \
  ? (W[((((d)>>1)*2+1)*12+(j))*3+0] + W[((((d)>>1)*2+0)*12+(j))*3+2]) \
  : (W[((((d)>>1)*2+0)*12+(j))*3+0] + xr[(j)] + W[(((((d)>>1)-1)*2+1)*12+(j))*3+2]))

// 6 RY gates on the reg-domain bits of the big-vector state (sl, par may be runtime)
#define GATES6(sl, par) do{ \
  _Pragma("unroll") \
  for (int lb = 0; lb < 6; lb++){ \
    const int wire_ = (par) ? (5 - lb) : (11 - lb); \
    vf2 cs_ = scsl[(sl)*12 + wire_]; \
    const float c_ = cs_.x, sn_ = cs_.y; \
    _Pragma("unroll") \
    for (int w0 = 0; w0 < 64; w0++){ \
      if (w0 & (1 << lb)) continue; \
      const int w1 = w0 | (1 << lb); \
      vf2 a_, b_, r0_, r1_; \
      a_.x = st[2*w0]; a_.y = st[2*w0+1]; \
      b_.x = st[2*w1]; b_.y = st[2*w1+1]; \
      r0_ = c_*a_ - sn_*b_; \
      r1_ = sn_*a_ + c_*b_; \
      st[2*w0] = r0_.x; st[2*w0+1] = r0_.y; \
      st[2*w1] = r1_.x; st[2*w1+1] = r1_.y; \
    } \
  } \
}while(0)

// swap lane-domain <-> reg-domain through LDS (conflict-free b64 writes / b128 reads);
// single wave -> in-order LDS pipe, no barrier needed
#define TRANSPOSE() do{ \
  _Pragma("unroll") \
  for (int w = 0; w < 64; w++){ \
    vf2 t_; t_.x = st[2*w]; t_.y = st[2*w+1]; \
    xbuf[w * ROWS + u] = t_; \
  } \
  _Pragma("unroll") \
  for (int j = 0; j < 32; j++){ \
    float4 f_ = ((const float4*)&xbuf[u * ROWS])[j]; \
    st[4*j] = f_.x; st[4*j+1] = f_.y; st[4*j+2] = f_.z; st[4*j+3] = f_.w; \
  } \
}while(0)

// merged diagonal d (runtime): reg part from tabs, lane part from ltab, cross CZ terms inline
#define DIAG(d, par) do{ \
  vf2 lp_ = ltab[(d)-1][u]; \
  vf2 lpn_ = -lp_; \
  const int u0_ = u & 1, u1_ = (u >> 1) & 1, u4_ = (u >> 4) & 1, u5_ = (u >> 5) & 1; \
  _Pragma("unroll") \
  for (int w = 0; w < 64; w++){ \
    vf2 dph_ = tabs[(d)-1][w]; \
    int sx_; \
    if (par) sx_ = ((w & 1) * u5_) ^ (((w >> 5) & 1) * u0_); \
    else     sx_ = (((w >> 5) & 1) * u1_) ^ (((w >> 4) & 1) * u0_) \
                 ^ (((w >> 1) & 1) * u5_) ^ ((w & 1) * u4_); \
    vf2 a_; a_.x = st[2*w]; a_.y = st[2*w+1]; \
    vf2 t_ = cmulv(a_, dph_); \
    vf2 r_ = cmulv(t_, sx_ ? lpn_ : lp_); \
    st[2*w] = r_.x; st[2*w+1] = r_.y; \
  } \
}while(0)

__global__ __attribute__((amdgpu_flat_work_group_size(64,64)))
__attribute__((amdgpu_waves_per_eu(1)))
void qiddm_wave(const float* __restrict__ gx,
                const float* __restrict__ gcw,
                const float* __restrict__ gcb,
                const float* __restrict__ gw1,
                const float* __restrict__ glw,
                const float* __restrict__ glb,
                float* __restrict__ gout)
{
  // One wave per sample; 4096-amp state in ONE ext_vector (mem2reg-guaranteed registers).
  // L0 layout: lane u = idx bits 11..6 (wires 0..5), reg w = idx bits 5..0 (wires 6..11)
  // L1 layout: lane u = idx bits 5..0,  reg w = idx bits 11..6
  __shared__ vf2 xbuf[64 * ROWS];   // 33792 B transpose buffer (aliases conv image)
  __shared__ vf2 tabs[5][64];       // reg-domain diagonal tables
  __shared__ vf2 ltab[5][64];       // lane-domain diagonal factors
  __shared__ vf2 scsl[72];          // (cos, sin) of theta/2 per (sublayer, wire)

  const int u = threadIdx.x;        // lane 0..63
  const int bid = blockIdx.x;

  float xr[12];                     // circuit inputs / expvals (constant-indexed only)

  // ---------- conv 3x3 s2 p1 + bias + GAP ----------
  {
    float* img = (float*)xbuf;
#pragma unroll
    for (int i = 0; i < 4; i++){
      float4 q4 = ((const float4*)gx)[(size_t)bid * 256 + i * 64 + u];
      ((float4*)img)[i * 64 + u] = q4;
    }
    float p[4][9];
#pragma unroll
    for (int i = 0; i < 4; i++){
      int pos = u + 64 * i, oi = pos >> 4, oj = pos & 15;
#pragma unroll
      for (int ki = 0; ki < 3; ki++)
#pragma unroll
        for (int kj = 0; kj < 3; kj++){
          int ri = 2*oi - 1 + ki, cj = 2*oj - 1 + kj;
          p[i][ki*3+kj] = (ri >= 0 && ri < 32 && cj >= 0 && cj < 32) ? img[ri*32+cj] : 0.0f;
        }
    }
#pragma unroll
    for (int q = 0; q < 12; q++){
      float a = 0.0f;
#pragma unroll
      for (int e = 0; e < 9; e++){
        float wv = gcw[q*9+e];                  // uniform -> scalarized
#pragma unroll
        for (int i = 0; i < 4; i++) a += p[i][e] * wv;
      }
#pragma unroll
      for (int off = 32; off; off >>= 1) a += __shfl_xor(a, off);
      xr[q] = gcb[q] + a * (1.0f/256.0f);
    }
  }

#pragma unroll 1
  for (int n = 0; n < 2; n++){
    const float* W = gw1 + n * 216;

    // ---- RY cos/sin table (72 gates) ----
#pragma unroll
    for (int rep = 0; rep < 2; rep++){
      int e = u + rep * 64;
      if (e < 72){
        float sv, cv; __sincosf(0.5f * W[e*3+1], &sv, &cv);
        vf2 cs; cs.x = cv; cs.y = sv; scsl[e] = cs;
      }
    }

    // ---- diagonal tables: reg-domain (tabs) and lane-domain (ltab), d unrolled ----
#pragma unroll
    for (int d = 1; d <= 5; d++){
      const int par = d & 1;                    // 1 -> applied in L1 (r=1), 0 -> L0 (r=2)
      const int r = par ? 1 : 2;
      {
        float ph = 0.0f;
#pragma unroll
        for (int lb = 0; lb < 6; lb++){
          int wire = par ? (5 - lb) : (11 - lb);          // reg-domain wires
          ph += ALPHA(d, wire) * ((float)((u >> lb) & 1) - 0.5f);
        }
        int idx_r = par ? (u << 6) : u;
        int y = ((idx_r << r) | (idx_r >> (12 - r))) & 0xFFF;
        int s = __popc(idx_r & y) & 1;                    // within-reg CZ parity
        float sv, cv; __sincosf(ph, &sv, &cv);
        vf2 e_; e_.x = cv; e_.y = sv; if (s) e_ = -e_;
        tabs[d-1][u] = e_;
      }
      {
        float ph = 0.0f;
#pragma unroll
        for (int lb = 0; lb < 6; lb++){
          int wire = par ? (11 - lb) : (5 - lb);          // lane-domain wires
          ph += ALPHA(d, wire) * ((float)((u >> lb) & 1) - 0.5f);
        }
        int idx_l = par ? u : (u << 6);
        int y = ((idx_l << r) | (idx_l >> (12 - r))) & 0xFFF;
        int s = __popc(idx_l & y) & 1;                    // within-lane CZ parity
        float sv, cv; __sincosf(ph, &sv, &cv);
        vf2 e_; e_.x = cv; e_.y = sv; if (s) e_ = -e_;
        ltab[d-1][u] = e_;
      }
    }

    // ---- circuit: |0>, 12 half-sublayer steps, measure ----
    v128f st;
#pragma unroll
    for (int w = 0; w < 64; w++){ st[2*w] = 0.f; st[2*w+1] = 0.f; }
    if (u == 0) st[0] = 1.f;                    // idx 0 = (lane 0, reg 0)

    GATES6(0, 0);                               // k=0: s0 on wires 6..11 (L0)
#pragma unroll 1
    for (int k = 1; k < 12; k++){
      const int sl  = k >> 1;
      const int par = ((k + 1) >> 1) & 1;
      if (k & 1) TRANSPOSE();                   // flip lane/reg domains
      else       DIAG(sl, par);                 // D_sl before the sublayer's 2nd half
      GATES6(sl, par);
    }

    // ---- measurement in L0 (final omega-diagonal is a pure phase: dropped) ----
    {
      float P = 0.f, mm[6] = {0.f,0.f,0.f,0.f,0.f,0.f};  // wires 6..11 (reg bits 5..0)
#pragma unroll
      for (int w = 0; w < 64; w++){
        float re = st[2*w], im = st[2*w+1];
        float pr = re*re + im*im;
        P += pr;
#pragma unroll
        for (int i = 0; i < 6; i++)
          mm[i] += ((w >> (5 - i)) & 1) ? -pr : pr;
      }
#pragma unroll
      for (int q = 0; q < 12; q++){
        float val = (q < 6) ? (((u >> (5 - q)) & 1) ? -P : P)   // wires 0..5 (lane bits)
                            : mm[q - 6];
#pragma unroll
        for (int off = 32; off; off >>= 1) val += __shfl_xor(val, off);
        xr[q] = val;                            // uniform across lanes after butterfly
      }
    }
  }

  // ---------- final linear ----------
  {
#pragma unroll
    for (int i = 0; i < 16; i++){
      int o = i * 64 + u;
      const float4* wr = (const float4*)(glw + o * 12);   // 48B rows, 16B aligned
      float4 w0 = wr[0], w1 = wr[1], w2 = wr[2];
      float a = glb[o];
      a += xr[0]*w0.x + xr[1]*w0.y + xr[2]*w0.z + xr[3]*w0.w;
      a += xr[4]*w1.x + xr[5]*w1.y + xr[6]*w1.z + xr[7]*w1.w;
      a += xr[8]*w2.x + xr[9]*w2.y + xr[10]*w2.z + xr[11]*w2.w;
      gout[(size_t)bid * 1024 + o] = a;
    }
  }
}

extern "C" void kernel_launch(void* const* d_in, const int* in_sizes, int n_in,
                              void* d_out, int out_size, void* d_ws, size_t ws_size,
                              hipStream_t stream)
{
  (void)n_in; (void)d_ws; (void)ws_size; (void)out_size;
  const float* x  = (const float*)d_in[0];
  const float* cw = (const float*)d_in[1];
  const float* cb = (const float*)d_in[2];
  const float* w1 = (const float*)d_in[3];
  const float* lw = (const float*)d_in[4];
  const float* lb = (const float*)d_in[5];
  float* out = (float*)d_out;
  const int nb = in_sizes[0] / 1024;   // 2048 samples, one wave each
  hipLaunchKernelGGL(qiddm_wave, dim3(nb), dim3(64), 0, stream,
                     x, cw, cb, w1, lw, lb, out);
}